// Round 4
// baseline (414.439 us; speedup 1.0000x reference)
//
#include <hip/hip_runtime.h>

// MultiheadAttention N=4096, d_model=512, 8 heads, d_head=64.
// fp32 inputs/output, bf16 MFMA pipeline.
// detect(mask dtype) ; pack_mask -> 2MB bits ; qkv GEMM (Q pre-scaled by
// 0.125*log2e, V written transposed per-head) ; split-KV flash attention
// (1 wave per block, wave-private LDS, zero barriers, zero shuffles) ;
// reduce partials ; output GEMM.

typedef __attribute__((ext_vector_type(8))) short bf16x8;
typedef __attribute__((ext_vector_type(4))) float f32x4;

#define N_TOK 4096
#define QSCALE 0.18033688f  // 0.125 * log2(e)

__device__ __forceinline__ unsigned short f2bf(float f) {
  unsigned u = __float_as_uint(f);
  return (unsigned short)((u + 0x7FFFu + ((u >> 16) & 1u)) >> 16);
}
__device__ __forceinline__ unsigned pack_bf16(float a, float b) {
  unsigned ua = __float_as_uint(a), ub = __float_as_uint(b);
  ua += 0x7FFFu + ((ua >> 16) & 1u);
  ub += 0x7FFFu + ((ub >> 16) & 1u);
  return (ua >> 16) | (ub & 0xFFFF0000u);
}
__device__ __forceinline__ f32x4 mfma16(bf16x8 a, bf16x8 b, f32x4 c) {
  return __builtin_amdgcn_mfma_f32_16x16x32_bf16(a, b, c, 0, 0, 0);
}
__device__ __forceinline__ float fast_exp2(float x) {
#if __has_builtin(__builtin_amdgcn_exp2f)
  return __builtin_amdgcn_exp2f(x);
#else
  return exp2f(x);
#endif
}

// ---------------- mask dtype sniff ------------------------------------------
__global__ __launch_bounds__(256) void detect_kernel(
    const unsigned* __restrict__ mask, unsigned* __restrict__ flags) {
  __shared__ int s_bad;
  int t = threadIdx.x;
  if (t == 0) s_bad = 0;
  __syncthreads();
  // 256 words = 1024 mask elems; if mask were u8-packed, P(all words in {0,1})
  // at 10% density is ~0. int32 storage -> words all in {0,1}.
  if (mask[t] > 1u) atomicOr(&s_bad, 1);
  __syncthreads();
  if (t == 0) {
    flags[0] = 0;
    flags[1] = s_bad ? 1u : 0u;
  }
}

// ---------------- mask bit-pack -> u64 bits[4096][64] ------------------------
__global__ __launch_bounds__(256) void pack_mask_kernel(
    const void* __restrict__ m, unsigned long long* __restrict__ bits,
    const unsigned* __restrict__ flags) {
  int gt = blockIdx.x * 256 + threadIdx.x;
  int wave = gt >> 6;
  int lane = threadIdx.x & 63;
  int base = wave * 256;
  unsigned long long b0, b1, b2, b3;
  if (flags[1]) {
    const unsigned char* m8 = (const unsigned char*)m;
    b0 = __ballot(m8[base + 0 * 64 + lane] != 0);
    b1 = __ballot(m8[base + 1 * 64 + lane] != 0);
    b2 = __ballot(m8[base + 2 * 64 + lane] != 0);
    b3 = __ballot(m8[base + 3 * 64 + lane] != 0);
  } else {
    const int* m4 = (const int*)m;
    b0 = __ballot(m4[base + 0 * 64 + lane] != 0);
    b1 = __ballot(m4[base + 1 * 64 + lane] != 0);
    b2 = __ballot(m4[base + 2 * 64 + lane] != 0);
    b3 = __ballot(m4[base + 3 * 64 + lane] != 0);
  }
  if (lane < 4) {
    unsigned long long bl = lane == 0 ? b0 : lane == 1 ? b1 : lane == 2 ? b2 : b3;
    bits[wave * 4 + lane] = bl;
  }
}

// ---------------- staging: 16 contiguous elems -> bf16 shorts ----------------
template <int F32>
__device__ __forceinline__ void load16(const void* base, int idx,
                                       unsigned short* dst) {
  if (F32) {
    const float* p = (const float*)base + idx;
    float4 f0 = *(const float4*)(p + 0);
    float4 f1 = *(const float4*)(p + 4);
    float4 f2 = *(const float4*)(p + 8);
    float4 f3 = *(const float4*)(p + 12);
    unsigned* d = (unsigned*)dst;
    d[0] = pack_bf16(f0.x, f0.y); d[1] = pack_bf16(f0.z, f0.w);
    d[2] = pack_bf16(f1.x, f1.y); d[3] = pack_bf16(f1.z, f1.w);
    d[4] = pack_bf16(f2.x, f2.y); d[5] = pack_bf16(f2.z, f2.w);
    d[6] = pack_bf16(f3.x, f3.y); d[7] = pack_bf16(f3.z, f3.w);
  } else {
    const unsigned short* p = (const unsigned short*)base + idx;
    *(uint4*)dst = *(const uint4*)p;
    *(uint4*)(dst + 8) = *(const uint4*)(p + 8);
  }
}

// ---------------- GEMM: out[n][o] = (sum_k A[n][k]*W[o][k] + bias[o])*scale --
// 128x128 tile, BK=64, 4 waves 2x2, 64x64/wave.
// TRANS=1: write bf16 transposed per-head: out[h=col>>6][col&63][token].
template <int A32, int O32, int TRANS>
__device__ __forceinline__ void gemm_body(
    const void* __restrict__ A, const float* __restrict__ W,
    const float* __restrict__ bias, void* __restrict__ out, float oscale) {
  __shared__ unsigned short As[128 * 72];
  __shared__ unsigned short Bs[128 * 72];
  const int t = threadIdx.x;
  const int lane = t & 63, w = t >> 6;
  const int wm = w & 1, wn = w >> 1;
  const int q4 = lane >> 4, i15 = lane & 15;
  const int m0 = blockIdx.y * 128, n0 = blockIdx.x * 128;
  f32x4 acc[4][4] = {};
  const int sr = t >> 2;
  const int sc = (t & 3) * 16;
  for (int k0 = 0; k0 < 512; k0 += 64) {
    __syncthreads();
#pragma unroll
    for (int p = 0; p < 2; ++p) {
      int row = sr + p * 64;
      unsigned short ta[16], tb[16];
      load16<A32>(A, (m0 + row) * 512 + k0 + sc, ta);
      load16<1>(W, (n0 + row) * 512 + k0 + sc, tb);
      *(uint4*)(As + row * 72 + sc) = *(uint4*)ta;
      *(uint4*)(As + row * 72 + sc + 8) = *(uint4*)(ta + 8);
      *(uint4*)(Bs + row * 72 + sc) = *(uint4*)tb;
      *(uint4*)(Bs + row * 72 + sc + 8) = *(uint4*)(tb + 8);
    }
    __syncthreads();
#pragma unroll
    for (int ks = 0; ks < 2; ++ks) {
      bf16x8 af[4], bfr[4];
#pragma unroll
      for (int mt = 0; mt < 4; ++mt)
        af[mt] = *(const bf16x8*)(As + (wm * 64 + mt * 16 + i15) * 72 + q4 * 8 + ks * 32);
#pragma unroll
      for (int nt = 0; nt < 4; ++nt)
        bfr[nt] = *(const bf16x8*)(Bs + (wn * 64 + nt * 16 + i15) * 72 + q4 * 8 + ks * 32);
#pragma unroll
      for (int mt = 0; mt < 4; ++mt)
#pragma unroll
        for (int nt = 0; nt < 4; ++nt)
          acc[mt][nt] = mfma16(af[mt], bfr[nt], acc[mt][nt]);
    }
  }
  // epilogue: C layout col = lane&15 (+16nt+64wn), row = quad*4+reg (+16mt+64wm)
#pragma unroll
  for (int nt = 0; nt < 4; ++nt) {
    int col = n0 + wn * 64 + nt * 16 + i15;
    float bv = bias[col];
    if (TRANS) {
      unsigned short* ob_ = (unsigned short*)out +
                            (size_t)(col >> 6) * (64 * N_TOK) +
                            (size_t)(col & 63) * N_TOK;
#pragma unroll
      for (int mt = 0; mt < 4; ++mt) {
        int rowb = m0 + wm * 64 + mt * 16 + q4 * 4;
        uint2 pr;
        pr.x = pack_bf16(acc[mt][nt][0] + bv, acc[mt][nt][1] + bv);
        pr.y = pack_bf16(acc[mt][nt][2] + bv, acc[mt][nt][3] + bv);
        *(uint2*)(ob_ + rowb) = pr;
      }
    } else {
#pragma unroll
      for (int mt = 0; mt < 4; ++mt) {
        int rowb = m0 + wm * 64 + mt * 16 + q4 * 4;
#pragma unroll
        for (int rr = 0; rr < 4; ++rr) {
          int idx = (rowb + rr) * 512 + col;
          float val = (acc[mt][nt][rr] + bv) * oscale;
          if (O32) ((float*)out)[idx] = val;
          else ((unsigned short*)out)[idx] = f2bf(val);
        }
      }
    }
  }
}

__global__ __launch_bounds__(256) void qkv_gemm_kernel(
    const float* __restrict__ q, const float* __restrict__ k,
    const float* __restrict__ v, const float* __restrict__ wq,
    const float* __restrict__ wk, const float* __restrict__ wv,
    const float* __restrict__ bq, const float* __restrict__ bk,
    const float* __restrict__ bv, unsigned short* __restrict__ outbase) {
  int z = blockIdx.z;
  if (z == 0) {
    gemm_body<1, 0, 0>(q, wq, bq, outbase, QSCALE);
  } else if (z == 1) {
    gemm_body<1, 0, 0>(k, wk, bk, outbase + (size_t)N_TOK * 512, 1.0f);
  } else {
    gemm_body<1, 0, 1>(v, wv, bv, outbase + 2ull * N_TOK * 512, 1.0f);
  }
}

__global__ __launch_bounds__(256) void out_gemm_kernel(
    const unsigned short* __restrict__ A, const float* __restrict__ W,
    const float* __restrict__ B, float* __restrict__ out) {
  gemm_body<0, 1, 0>(A, W, B, out, 1.0f);
}

// ---------------- split-KV flash attention -----------------------------------
// One wave per block (64 threads). Wave owns 64 q-rows x head x 1024-j chunk.
// Per 64-j tile: stage K[64j][64d] and Vt[64d][64 k-slots] in wave-private LDS
// (no barriers at all); S^T = K*Q^T (4 j-groups x 4 i-groups); p = exp2 with
// mask select-to--200; PV B-frag = lane's own packed-exp regs (V k-order
// permuted at staging so no cross-lane transport); O^T += V^T*P^T.
// Partials (fp32 numerator + denominator) written per chunk.
__global__ __launch_bounds__(64, 2) void attn_kernel(
    const unsigned short* __restrict__ qp, const unsigned short* __restrict__ kp,
    const unsigned short* __restrict__ vpT,
    const unsigned long long* __restrict__ mbits,
    float* __restrict__ Op, float* __restrict__ dp) {
  __shared__ unsigned short Ks[64 * 64];  // [j][d-granule swizzled]
  __shared__ unsigned short Vt[64 * 64];  // [d][k-slot swizzled, j-permuted]
  const int l = threadIdx.x;
  const int q4 = l >> 4, i15 = l & 15;
  const int bx = blockIdx.x;
  const int ig = bx & 63;
  const int head = (bx >> 6) & 7;
  const int chunk = bx >> 9;
  const int i0 = ig * 64;
  const int ch = head * 64;
  const int ji = l >> 3;  // staging: row-within-8
  const int sg = l & 7;   // staging: granule
  // Q B-fragments in registers for the whole kernel
  bf16x8 qf[4][2];
#pragma unroll
  for (int nt = 0; nt < 4; ++nt) {
    const unsigned short* qr = qp + (size_t)(i0 + nt * 16 + i15) * 512 + ch;
#pragma unroll
    for (int ks = 0; ks < 2; ++ks)
      qf[nt][ks] = *(const bf16x8*)(qr + ks * 32 + q4 * 8);
  }
  const unsigned long long* mrow[4];
#pragma unroll
  for (int nt = 0; nt < 4; ++nt)
    mrow[nt] = mbits + (size_t)(i0 + nt * 16 + i15) * 64;
  f32x4 oacc[4][4] = {};  // [mtd][nt]
  float den[4] = {0.f, 0.f, 0.f, 0.f};
  const unsigned short* vbase = vpT + (size_t)head * (64 * N_TOK);
  // prefetch tile 0
  uint4 kst[8], vst[8];
  {
    int j0 = chunk * 1024;
#pragma unroll
    for (int r = 0; r < 8; ++r) {
      int row = r * 8 + ji;
      kst[r] = *(const uint4*)(kp + (size_t)(j0 + row) * 512 + ch + sg * 8);
      vst[r] = *(const uint4*)(vbase + (size_t)row * N_TOK + j0 + sg * 8);
    }
  }
  for (int jt = 0; jt < 16; ++jt) {
    const int j0 = chunk * 1024 + jt * 64;
    // ---- write staged tile to LDS (granule-XOR swizzles)
#pragma unroll
    for (int r = 0; r < 8; ++r) {
      int row = r * 8 + ji;
      *(uint4*)(Ks + row * 64 + ((sg ^ ji ^ r) * 8)) = kst[r];
      const unsigned* vs = (const unsigned*)&vst[r];
#pragma unroll
      for (int rr = 0; rr < 2; ++rr) {
        int kg = (sg >> 2) * 4 + (sg & 1) * 2 + rr;  // k-granule (j-permuted)
        int hh = (sg >> 1) & 1;                      // within-granule half
        *(uint2*)(Vt + row * 64 + ((kg ^ ji ^ r) * 8) + hh * 4) =
            make_uint2(vs[rr * 2], vs[rr * 2 + 1]);
      }
    }
    // ---- prefetch next tile (wraps harmlessly on last iter)
    {
      int jn = chunk * 1024 + ((jt + 1) & 15) * 64;
#pragma unroll
      for (int r = 0; r < 8; ++r) {
        int row = r * 8 + ji;
        kst[r] = *(const uint4*)(kp + (size_t)(jn + row) * 512 + ch + sg * 8);
        vst[r] = *(const uint4*)(vbase + (size_t)row * N_TOK + jn + sg * 8);
      }
    }
    // ---- mask words for this tile
    unsigned long long mw[4];
    int widx = j0 >> 6;
#pragma unroll
    for (int nt = 0; nt < 4; ++nt) mw[nt] = mrow[nt][widx];
    // ---- K fragments
    bf16x8 Kf[4][2];
#pragma unroll
    for (int mtj = 0; mtj < 4; ++mtj) {
      int js = mtj * 16 + i15;
#pragma unroll
      for (int ksd = 0; ksd < 2; ++ksd) {
        int g = ksd * 4 + q4;
        Kf[mtj][ksd] =
            *(const bf16x8*)(Ks + js * 64 + ((g ^ (js & 7) ^ (js >> 3)) * 8));
      }
    }
    // ---- phase 1: S^T + exp for all i-groups
    unsigned pk[4][8];
#pragma unroll
    for (int nt = 0; nt < 4; ++nt) {
      float dsum = 0.f;
#pragma unroll
      for (int mtj = 0; mtj < 4; ++mtj) {
        f32x4 s = {0.f, 0.f, 0.f, 0.f};
        s = mfma16(Kf[mtj][0], qf[nt][0], s);
        s = mfma16(Kf[mtj][1], qf[nt][1], s);
        unsigned nib = (unsigned)(mw[nt] >> (mtj * 16 + q4 * 4)) & 15u;
        float p0 = fast_exp2((nib & 1u) ? -200.f : s[0]);
        float p1 = fast_exp2((nib & 2u) ? -200.f : s[1]);
        float p2 = fast_exp2((nib & 4u) ? -200.f : s[2]);
        float p3 = fast_exp2((nib & 8u) ? -200.f : s[3]);
        dsum += (p0 + p1) + (p2 + p3);
        pk[nt][mtj * 2] = pack_bf16(p0, p1);
        pk[nt][mtj * 2 + 1] = pack_bf16(p2, p3);
      }
      den[nt] += dsum;
    }
    // ---- V fragments (k-slot order matches pk concatenation)
    bf16x8 Vf[2][4];
#pragma unroll
    for (int ks = 0; ks < 2; ++ks)
#pragma unroll
      for (int mtd = 0; mtd < 4; ++mtd) {
        int d = mtd * 16 + i15;
        int kg = ks * 4 + q4;
        Vf[ks][mtd] =
            *(const bf16x8*)(Vt + d * 64 + ((kg ^ (d & 7) ^ (d >> 3)) * 8));
      }
    // ---- phase 2: PV (B-frag = lane's own pk regs, zero transport)
#pragma unroll
    for (int nt = 0; nt < 4; ++nt) {
      union { unsigned u[4]; bf16x8 v; } pf0, pf1;
      pf0.u[0] = pk[nt][0]; pf0.u[1] = pk[nt][1];
      pf0.u[2] = pk[nt][2]; pf0.u[3] = pk[nt][3];
      pf1.u[0] = pk[nt][4]; pf1.u[1] = pk[nt][5];
      pf1.u[2] = pk[nt][6]; pf1.u[3] = pk[nt][7];
#pragma unroll
      for (int mtd = 0; mtd < 4; ++mtd) {
        oacc[mtd][nt] = mfma16(Vf[0][mtd], pf0.v, oacc[mtd][nt]);
        oacc[mtd][nt] = mfma16(Vf[1][mtd], pf1.v, oacc[mtd][nt]);
      }
    }
  }
  // ---- write fp32 partials
  float* Opc = Op + (size_t)chunk * N_TOK * 512;
#pragma unroll
  for (int nt = 0; nt < 4; ++nt) {
    float dn = den[nt];
    dn += __shfl_xor(dn, 16);
    dn += __shfl_xor(dn, 32);
    int row = i0 + nt * 16 + i15;
#pragma unroll
    for (int mtd = 0; mtd < 4; ++mtd)
      *(f32x4*)(Opc + (size_t)row * 512 + ch + mtd * 16 + q4 * 4) =
          oacc[mtd][nt];
    if (q4 == 0) dp[(size_t)(chunk * 8 + head) * N_TOK + row] = dn;
  }
}

// ---------------- combine split-KV partials -> bf16 attention output ---------
__global__ __launch_bounds__(256) void reduce_kernel(
    const float* __restrict__ Op, const float* __restrict__ dp,
    unsigned short* __restrict__ ob) {
  int x = blockIdx.x * 256 + threadIdx.x;  // 0..524287
  int i = x >> 7;
  int c = (x & 127) * 4;
  size_t off = (size_t)i * 512 + c;
  const size_t CH = (size_t)N_TOK * 512;
  float4 a0 = *(const float4*)(Op + off);
  float4 a1 = *(const float4*)(Op + CH + off);
  float4 a2 = *(const float4*)(Op + 2 * CH + off);
  float4 a3 = *(const float4*)(Op + 3 * CH + off);
  int h = c >> 6;
  float den = dp[(size_t)h * N_TOK + i] + dp[(size_t)(8 + h) * N_TOK + i] +
              dp[(size_t)(16 + h) * N_TOK + i] + dp[(size_t)(24 + h) * N_TOK + i];
  float inv = 1.0f / den;
  float sx = (a0.x + a1.x + a2.x + a3.x) * inv;
  float sy = (a0.y + a1.y + a2.y + a3.y) * inv;
  float sz = (a0.z + a1.z + a2.z + a3.z) * inv;
  float sw = (a0.w + a1.w + a2.w + a3.w) * inv;
  uint2 o;
  o.x = pack_bf16(sx, sy);
  o.y = pack_bf16(sz, sw);
  *(uint2*)(ob + off) = o;
}

// ---------------- launch -----------------------------------------------------
extern "C" void kernel_launch(void* const* d_in, const int* in_sizes, int n_in,
                              void* d_out, int out_size, void* d_ws, size_t ws_size,
                              hipStream_t stream) {
  const float* q = (const float*)d_in[0];
  const float* k = (const float*)d_in[1];
  const float* v = (const float*)d_in[2];
  const void* mask = d_in[3];
  const float* wq = (const float*)d_in[4];
  const float* bq = (const float*)d_in[5];
  const float* wk = (const float*)d_in[6];
  const float* bk = (const float*)d_in[7];
  const float* wv = (const float*)d_in[8];
  const float* bv = (const float*)d_in[9];
  const float* wo = (const float*)d_in[10];
  const float* bo = (const float*)d_in[11];

  char* ws = (char*)d_ws;
  unsigned* flags = (unsigned*)ws;                                    // 4 KiB
  unsigned long long* mb = (unsigned long long*)(ws + 4096);          // 2 MiB
  unsigned short* qkvp = (unsigned short*)(ws + 4096 + (2ull << 20)); // 12 MiB: qp, kp, vpT
  unsigned short* ob = qkvp + 3ull * N_TOK * 512;                     // 4 MiB
  float* Op = (float*)(ob + (size_t)N_TOK * 512);                     // 32 MiB
  float* dp = Op + 4ull * N_TOK * 512;                                // 512 KiB

  detect_kernel<<<1, 256, 0, stream>>>((const unsigned*)mask, flags);
  pack_mask_kernel<<<16384, 256, 0, stream>>>(mask, mb, flags);
  qkv_gemm_kernel<<<dim3(4, 32, 3), 256, 0, stream>>>(q, k, v, wq, wk, wv, bq,
                                                      bk, bv, qkvp);
  attn_kernel<<<2048, 64, 0, stream>>>(
      qkvp, qkvp + (size_t)N_TOK * 512, qkvp + 2ull * N_TOK * 512, mb, Op, dp);
  reduce_kernel<<<2048, 256, 0, stream>>>(Op, dp, ob);
  out_gemm_kernel<<<dim3(4, 32), 256, 0, stream>>>(ob, wo, bo, (float*)d_out);
}

// Round 5
// 264.779 us; speedup vs baseline: 1.5652x; 1.5652x over previous
//
#include <hip/hip_runtime.h>

// MultiheadAttention N=4096, d_model=512, 8 heads, d_head=64.
// fp32 inputs/output, bf16 MFMA pipeline.
// detect(mask dtype) ; pack_mask -> 2MB bits ; qkv GEMM (Q pre-scaled by
// 0.125*log2e, V written transposed per-head) ; split-KV flash attention
// (4-wave blocks, cooperative double-buffered K/V staging, zero-shuffle PV) ;
// reduce partials ; output GEMM.

typedef __attribute__((ext_vector_type(8))) short bf16x8;
typedef __attribute__((ext_vector_type(4))) float f32x4;

#define N_TOK 4096
#define QSCALE 0.18033688f  // 0.125 * log2(e)

__device__ __forceinline__ unsigned short f2bf(float f) {
  unsigned u = __float_as_uint(f);
  return (unsigned short)((u + 0x7FFFu + ((u >> 16) & 1u)) >> 16);
}
__device__ __forceinline__ unsigned pack_bf16(float a, float b) {
  unsigned ua = __float_as_uint(a), ub = __float_as_uint(b);
  ua += 0x7FFFu + ((ua >> 16) & 1u);
  ub += 0x7FFFu + ((ub >> 16) & 1u);
  return (ua >> 16) | (ub & 0xFFFF0000u);
}
__device__ __forceinline__ f32x4 mfma16(bf16x8 a, bf16x8 b, f32x4 c) {
  return __builtin_amdgcn_mfma_f32_16x16x32_bf16(a, b, c, 0, 0, 0);
}
__device__ __forceinline__ float fast_exp2(float x) {
#if __has_builtin(__builtin_amdgcn_exp2f)
  return __builtin_amdgcn_exp2f(x);
#else
  return exp2f(x);
#endif
}

// ---------------- mask dtype sniff ------------------------------------------
__global__ __launch_bounds__(256) void detect_kernel(
    const unsigned* __restrict__ mask, unsigned* __restrict__ flags) {
  __shared__ int s_bad;
  int t = threadIdx.x;
  if (t == 0) s_bad = 0;
  __syncthreads();
  if (mask[t] > 1u) atomicOr(&s_bad, 1);
  __syncthreads();
  if (t == 0) {
    flags[0] = 0;
    flags[1] = s_bad ? 1u : 0u;
  }
}

// ---------------- mask bit-pack -> u64 bits[4096][64] ------------------------
__global__ __launch_bounds__(256) void pack_mask_kernel(
    const void* __restrict__ m, unsigned long long* __restrict__ bits,
    const unsigned* __restrict__ flags) {
  int gt = blockIdx.x * 256 + threadIdx.x;
  int wave = gt >> 6;
  int lane = threadIdx.x & 63;
  int base = wave * 256;
  unsigned long long b0, b1, b2, b3;
  if (flags[1]) {
    const unsigned char* m8 = (const unsigned char*)m;
    b0 = __ballot(m8[base + 0 * 64 + lane] != 0);
    b1 = __ballot(m8[base + 1 * 64 + lane] != 0);
    b2 = __ballot(m8[base + 2 * 64 + lane] != 0);
    b3 = __ballot(m8[base + 3 * 64 + lane] != 0);
  } else {
    const int* m4 = (const int*)m;
    b0 = __ballot(m4[base + 0 * 64 + lane] != 0);
    b1 = __ballot(m4[base + 1 * 64 + lane] != 0);
    b2 = __ballot(m4[base + 2 * 64 + lane] != 0);
    b3 = __ballot(m4[base + 3 * 64 + lane] != 0);
  }
  if (lane < 4) {
    unsigned long long bl = lane == 0 ? b0 : lane == 1 ? b1 : lane == 2 ? b2 : b3;
    bits[wave * 4 + lane] = bl;
  }
}

// ---------------- staging: 16 contiguous elems -> bf16 shorts ----------------
template <int F32>
__device__ __forceinline__ void load16(const void* base, int idx,
                                       unsigned short* dst) {
  if (F32) {
    const float* p = (const float*)base + idx;
    float4 f0 = *(const float4*)(p + 0);
    float4 f1 = *(const float4*)(p + 4);
    float4 f2 = *(const float4*)(p + 8);
    float4 f3 = *(const float4*)(p + 12);
    unsigned* d = (unsigned*)dst;
    d[0] = pack_bf16(f0.x, f0.y); d[1] = pack_bf16(f0.z, f0.w);
    d[2] = pack_bf16(f1.x, f1.y); d[3] = pack_bf16(f1.z, f1.w);
    d[4] = pack_bf16(f2.x, f2.y); d[5] = pack_bf16(f2.z, f2.w);
    d[6] = pack_bf16(f3.x, f3.y); d[7] = pack_bf16(f3.z, f3.w);
  } else {
    const unsigned short* p = (const unsigned short*)base + idx;
    *(uint4*)dst = *(const uint4*)p;
    *(uint4*)(dst + 8) = *(const uint4*)(p + 8);
  }
}

// ---------------- GEMM: out[n][o] = (sum_k A[n][k]*W[o][k] + bias[o])*scale --
// 128x128 tile, BK=64, 4 waves 2x2, 64x64/wave.
// TRANS=1: write bf16 transposed per-head: out[h=col>>6][col&63][token].
template <int A32, int O32, int TRANS>
__device__ __forceinline__ void gemm_body(
    const void* __restrict__ A, const float* __restrict__ W,
    const float* __restrict__ bias, void* __restrict__ out, float oscale) {
  __shared__ unsigned short As[128 * 72];
  __shared__ unsigned short Bs[128 * 72];
  const int t = threadIdx.x;
  const int lane = t & 63, w = t >> 6;
  const int wm = w & 1, wn = w >> 1;
  const int q4 = lane >> 4, i15 = lane & 15;
  const int m0 = blockIdx.y * 128, n0 = blockIdx.x * 128;
  f32x4 acc[4][4] = {};
  const int sr = t >> 2;
  const int sc = (t & 3) * 16;
  for (int k0 = 0; k0 < 512; k0 += 64) {
    __syncthreads();
#pragma unroll
    for (int p = 0; p < 2; ++p) {
      int row = sr + p * 64;
      unsigned short ta[16], tb[16];
      load16<A32>(A, (m0 + row) * 512 + k0 + sc, ta);
      load16<1>(W, (n0 + row) * 512 + k0 + sc, tb);
      *(uint4*)(As + row * 72 + sc) = *(uint4*)ta;
      *(uint4*)(As + row * 72 + sc + 8) = *(uint4*)(ta + 8);
      *(uint4*)(Bs + row * 72 + sc) = *(uint4*)tb;
      *(uint4*)(Bs + row * 72 + sc + 8) = *(uint4*)(tb + 8);
    }
    __syncthreads();
#pragma unroll
    for (int ks = 0; ks < 2; ++ks) {
      bf16x8 af[4], bfr[4];
#pragma unroll
      for (int mt = 0; mt < 4; ++mt)
        af[mt] = *(const bf16x8*)(As + (wm * 64 + mt * 16 + i15) * 72 + q4 * 8 + ks * 32);
#pragma unroll
      for (int nt = 0; nt < 4; ++nt)
        bfr[nt] = *(const bf16x8*)(Bs + (wn * 64 + nt * 16 + i15) * 72 + q4 * 8 + ks * 32);
#pragma unroll
      for (int mt = 0; mt < 4; ++mt)
#pragma unroll
        for (int nt = 0; nt < 4; ++nt)
          acc[mt][nt] = mfma16(af[mt], bfr[nt], acc[mt][nt]);
    }
  }
  // epilogue: C layout col = lane&15 (+16nt+64wn), row = quad*4+reg (+16mt+64wm)
#pragma unroll
  for (int nt = 0; nt < 4; ++nt) {
    int col = n0 + wn * 64 + nt * 16 + i15;
    float bv = bias[col];
    if (TRANS) {
      unsigned short* ob_ = (unsigned short*)out +
                            (size_t)(col >> 6) * (64 * N_TOK) +
                            (size_t)(col & 63) * N_TOK;
#pragma unroll
      for (int mt = 0; mt < 4; ++mt) {
        int rowb = m0 + wm * 64 + mt * 16 + q4 * 4;
        uint2 pr;
        pr.x = pack_bf16(acc[mt][nt][0] + bv, acc[mt][nt][1] + bv);
        pr.y = pack_bf16(acc[mt][nt][2] + bv, acc[mt][nt][3] + bv);
        *(uint2*)(ob_ + rowb) = pr;
      }
    } else {
#pragma unroll
      for (int mt = 0; mt < 4; ++mt) {
        int rowb = m0 + wm * 64 + mt * 16 + q4 * 4;
#pragma unroll
        for (int rr = 0; rr < 4; ++rr) {
          int idx = (rowb + rr) * 512 + col;
          float val = (acc[mt][nt][rr] + bv) * oscale;
          if (O32) ((float*)out)[idx] = val;
          else ((unsigned short*)out)[idx] = f2bf(val);
        }
      }
    }
  }
}

__global__ __launch_bounds__(256) void qkv_gemm_kernel(
    const float* __restrict__ q, const float* __restrict__ k,
    const float* __restrict__ v, const float* __restrict__ wq,
    const float* __restrict__ wk, const float* __restrict__ wv,
    const float* __restrict__ bq, const float* __restrict__ bk,
    const float* __restrict__ bv, unsigned short* __restrict__ outbase) {
  int z = blockIdx.z;
  if (z == 0) {
    gemm_body<1, 0, 0>(q, wq, bq, outbase, QSCALE);
  } else if (z == 1) {
    gemm_body<1, 0, 0>(k, wk, bk, outbase + (size_t)N_TOK * 512, 1.0f);
  } else {
    gemm_body<1, 0, 1>(v, wv, bv, outbase + 2ull * N_TOK * 512, 1.0f);
  }
}

__global__ __launch_bounds__(256) void out_gemm_kernel(
    const unsigned short* __restrict__ A, const float* __restrict__ W,
    const float* __restrict__ B, float* __restrict__ out) {
  gemm_body<0, 1, 0>(A, W, B, out, 1.0f);
}

// ---------------- split-KV flash attention -----------------------------------
// Block: 256 threads = 4 waves; covers 256 q-rows x head x 1024-j chunk.
// Per 64-j tile: K[64j][64d] and Vt[64d][64 k-slots] staged cooperatively
// (wave w stages rows 16w..16w+15) into double-buffered LDS; ONE barrier per
// tile; global prefetch of tile t+1 in registers. Each wave computes its own
// 64 q-rows: S^T = K*Q^T, p = exp2 (mask select-to--200), PV B-frag = lane's
// own packed-exp regs (V k-order permuted at staging -> zero cross-lane
// transport), O^T += V^T*P^T. fp32 partials per chunk.
__global__ __launch_bounds__(256, 2) void attn_kernel(
    const unsigned short* __restrict__ qp, const unsigned short* __restrict__ kp,
    const unsigned short* __restrict__ vpT,
    const unsigned long long* __restrict__ mbits,
    float* __restrict__ Op, float* __restrict__ dp) {
  __shared__ unsigned short Ks[2][64 * 64];  // [buf][j][d-granule swizzled]
  __shared__ unsigned short Vt[2][64 * 64];  // [buf][d][k-slot swizzled]
  const int t = threadIdx.x;
  const int l = t & 63, w = t >> 6;
  const int q4 = l >> 4, i15 = l & 15;
  const int iblk = blockIdx.x * 256;
  const int head = blockIdx.y;
  const int chunk = blockIdx.z;
  const int ch = head * 64;
  const int i0 = iblk + w * 64;   // this wave's q-row base
  const int ji = l >> 3;          // staging: row-within-8
  const int sg = l & 7;           // staging: source granule
  const int r0 = w * 2;           // this wave stages r = r0, r0+1 (rows 16w..16w+15)
  const int j0base = chunk * 1024;
  // Q B-fragments in registers for the whole kernel
  bf16x8 qf[4][2];
#pragma unroll
  for (int nt = 0; nt < 4; ++nt) {
    const unsigned short* qr = qp + (size_t)(i0 + nt * 16 + i15) * 512 + ch;
#pragma unroll
    for (int ks = 0; ks < 2; ++ks)
      qf[nt][ks] = *(const bf16x8*)(qr + ks * 32 + q4 * 8);
  }
  const unsigned long long* mrow[4];
#pragma unroll
  for (int nt = 0; nt < 4; ++nt)
    mrow[nt] = mbits + (size_t)(i0 + nt * 16 + i15) * 64;
  f32x4 oacc[4][4] = {};  // [mtd][nt]
  float den[4] = {0.f, 0.f, 0.f, 0.f};
  const unsigned short* vbase = vpT + (size_t)head * (64 * N_TOK);
  // prefetch tile 0 (wave's quarter)
  uint4 kst[2], vst[2];
#pragma unroll
  for (int rr = 0; rr < 2; ++rr) {
    int row = (r0 + rr) * 8 + ji;
    kst[rr] = *(const uint4*)(kp + (size_t)(j0base + row) * 512 + ch + sg * 8);
    vst[rr] = *(const uint4*)(vbase + (size_t)row * N_TOK + j0base + sg * 8);
  }
  for (int jt = 0; jt < 16; ++jt) {
    unsigned short* KsB = Ks[jt & 1];
    unsigned short* VtB = Vt[jt & 1];
    // ---- write staged quarter to LDS (granule-XOR swizzles)
#pragma unroll
    for (int rr = 0; rr < 2; ++rr) {
      int r = r0 + rr;
      int row = r * 8 + ji;
      *(uint4*)(KsB + row * 64 + ((sg ^ ji ^ r) * 8)) = kst[rr];
      const unsigned* vs = (const unsigned*)&vst[rr];
#pragma unroll
      for (int c2 = 0; c2 < 2; ++c2) {
        int kg = (sg >> 2) * 4 + (sg & 1) * 2 + c2;  // k-granule (j-permuted)
        int hh = (sg >> 1) & 1;                      // within-granule half
        *(uint2*)(VtB + row * 64 + ((kg ^ ji ^ r) * 8) + hh * 4) =
            make_uint2(vs[c2 * 2], vs[c2 * 2 + 1]);
      }
    }
    __syncthreads();
    // ---- prefetch next tile (wraps harmlessly on last iter)
    {
      int jn = j0base + ((jt + 1) & 15) * 64;
#pragma unroll
      for (int rr = 0; rr < 2; ++rr) {
        int row = (r0 + rr) * 8 + ji;
        kst[rr] = *(const uint4*)(kp + (size_t)(jn + row) * 512 + ch + sg * 8);
        vst[rr] = *(const uint4*)(vbase + (size_t)row * N_TOK + jn + sg * 8);
      }
    }
    // ---- mask words for this tile
    unsigned long long mw[4];
    int widx = chunk * 16 + jt;
#pragma unroll
    for (int nt = 0; nt < 4; ++nt) mw[nt] = mrow[nt][widx];
    // ---- K fragments
    bf16x8 Kf[4][2];
#pragma unroll
    for (int mtj = 0; mtj < 4; ++mtj) {
      int js = mtj * 16 + i15;
#pragma unroll
      for (int ksd = 0; ksd < 2; ++ksd) {
        int g = ksd * 4 + q4;
        Kf[mtj][ksd] =
            *(const bf16x8*)(KsB + js * 64 + ((g ^ (js & 7) ^ (js >> 3)) * 8));
      }
    }
    // ---- phase 1: S^T + exp for all i-groups
    unsigned pk[4][8];
#pragma unroll
    for (int nt = 0; nt < 4; ++nt) {
      float dsum = 0.f;
#pragma unroll
      for (int mtj = 0; mtj < 4; ++mtj) {
        f32x4 s = {0.f, 0.f, 0.f, 0.f};
        s = mfma16(Kf[mtj][0], qf[nt][0], s);
        s = mfma16(Kf[mtj][1], qf[nt][1], s);
        unsigned nib = (unsigned)(mw[nt] >> (mtj * 16 + q4 * 4)) & 15u;
        float p0 = fast_exp2((nib & 1u) ? -200.f : s[0]);
        float p1 = fast_exp2((nib & 2u) ? -200.f : s[1]);
        float p2 = fast_exp2((nib & 4u) ? -200.f : s[2]);
        float p3 = fast_exp2((nib & 8u) ? -200.f : s[3]);
        dsum += (p0 + p1) + (p2 + p3);
        pk[nt][mtj * 2] = pack_bf16(p0, p1);
        pk[nt][mtj * 2 + 1] = pack_bf16(p2, p3);
      }
      den[nt] += dsum;
    }
    // ---- V fragments (k-slot order matches pk concatenation)
    bf16x8 Vf[2][4];
#pragma unroll
    for (int ks = 0; ks < 2; ++ks)
#pragma unroll
      for (int mtd = 0; mtd < 4; ++mtd) {
        int d = mtd * 16 + i15;
        int kg = ks * 4 + q4;
        Vf[ks][mtd] =
            *(const bf16x8*)(VtB + d * 64 + ((kg ^ (d & 7) ^ (d >> 3)) * 8));
      }
    // ---- phase 2: PV (B-frag = lane's own pk regs, zero transport)
#pragma unroll
    for (int nt = 0; nt < 4; ++nt) {
      union { unsigned u[4]; bf16x8 v; } pf0, pf1;
      pf0.u[0] = pk[nt][0]; pf0.u[1] = pk[nt][1];
      pf0.u[2] = pk[nt][2]; pf0.u[3] = pk[nt][3];
      pf1.u[0] = pk[nt][4]; pf1.u[1] = pk[nt][5];
      pf1.u[2] = pk[nt][6]; pf1.u[3] = pk[nt][7];
#pragma unroll
      for (int mtd = 0; mtd < 4; ++mtd) {
        oacc[mtd][nt] = mfma16(Vf[0][mtd], pf0.v, oacc[mtd][nt]);
        oacc[mtd][nt] = mfma16(Vf[1][mtd], pf1.v, oacc[mtd][nt]);
      }
    }
  }
  // ---- write fp32 partials: Op[chunk][head][i][64], dp[chunk][head][i]
  float* Opc = Op + ((size_t)(chunk * 8 + head) * N_TOK) * 64;
#pragma unroll
  for (int nt = 0; nt < 4; ++nt) {
    float dn = den[nt];
    dn += __shfl_xor(dn, 16);
    dn += __shfl_xor(dn, 32);
    int row = i0 + nt * 16 + i15;
#pragma unroll
    for (int mtd = 0; mtd < 4; ++mtd)
      *(f32x4*)(Opc + (size_t)row * 64 + mtd * 16 + q4 * 4) = oacc[mtd][nt];
    if (q4 == 0) dp[(size_t)(chunk * 8 + head) * N_TOK + row] = dn;
  }
}

// ---------------- combine split-KV partials -> bf16 attention output ---------
__global__ __launch_bounds__(256) void reduce_kernel(
    const float* __restrict__ Op, const float* __restrict__ dp,
    unsigned short* __restrict__ ob) {
  int x = blockIdx.x * 256 + threadIdx.x;  // 0..524287
  int i = x >> 7;
  int c = (x & 127) * 4;
  int h = c >> 6;
  int d = c & 63;
  const size_t CH = (size_t)8 * N_TOK * 64;  // floats per chunk
  size_t base = ((size_t)h * N_TOK + i) * 64 + d;
  float4 a0 = *(const float4*)(Op + base);
  float4 a1 = *(const float4*)(Op + CH + base);
  float4 a2 = *(const float4*)(Op + 2 * CH + base);
  float4 a3 = *(const float4*)(Op + 3 * CH + base);
  float den = dp[(size_t)h * N_TOK + i] + dp[(size_t)(8 + h) * N_TOK + i] +
              dp[(size_t)(16 + h) * N_TOK + i] + dp[(size_t)(24 + h) * N_TOK + i];
  float inv = 1.0f / den;
  float sx = (a0.x + a1.x + a2.x + a3.x) * inv;
  float sy = (a0.y + a1.y + a2.y + a3.y) * inv;
  float sz = (a0.z + a1.z + a2.z + a3.z) * inv;
  float sw = (a0.w + a1.w + a2.w + a3.w) * inv;
  uint2 o;
  o.x = pack_bf16(sx, sy);
  o.y = pack_bf16(sz, sw);
  *(uint2*)(ob + (size_t)i * 512 + c) = o;
}

// ---------------- launch -----------------------------------------------------
extern "C" void kernel_launch(void* const* d_in, const int* in_sizes, int n_in,
                              void* d_out, int out_size, void* d_ws, size_t ws_size,
                              hipStream_t stream) {
  const float* q = (const float*)d_in[0];
  const float* k = (const float*)d_in[1];
  const float* v = (const float*)d_in[2];
  const void* mask = d_in[3];
  const float* wq = (const float*)d_in[4];
  const float* bq = (const float*)d_in[5];
  const float* wk = (const float*)d_in[6];
  const float* bk = (const float*)d_in[7];
  const float* wv = (const float*)d_in[8];
  const float* bv = (const float*)d_in[9];
  const float* wo = (const float*)d_in[10];
  const float* bo = (const float*)d_in[11];

  char* ws = (char*)d_ws;
  unsigned* flags = (unsigned*)ws;                                    // 4 KiB
  unsigned long long* mb = (unsigned long long*)(ws + 4096);          // 2 MiB
  unsigned short* qkvp = (unsigned short*)(ws + 4096 + (2ull << 20)); // 12 MiB: qp, kp, vpT
  unsigned short* ob = qkvp + 3ull * N_TOK * 512;                     // 4 MiB
  float* Op = (float*)(ob + (size_t)N_TOK * 512);                     // 32 MiB
  float* dp = Op + 4ull * 8 * N_TOK * 64;                             // 512 KiB

  detect_kernel<<<1, 256, 0, stream>>>((const unsigned*)mask, flags);
  pack_mask_kernel<<<16384, 256, 0, stream>>>(mask, mb, flags);
  qkv_gemm_kernel<<<dim3(4, 32, 3), 256, 0, stream>>>(q, k, v, wq, wk, wv, bq,
                                                      bk, bv, qkvp);
  attn_kernel<<<dim3(16, 8, 4), 256, 0, stream>>>(
      qkvp, qkvp + (size_t)N_TOK * 512, qkvp + 2ull * N_TOK * 512, mb, Op, dp);
  reduce_kernel<<<2048, 256, 0, stream>>>(Op, dp, ob);
  out_gemm_kernel<<<dim3(4, 32), 256, 0, stream>>>(ob, wo, bo, (float*)d_out);
}